// Round 5
// baseline (237.483 us; speedup 1.0000x reference)
//
#include <hip/hip_runtime.h>
#include <stdint.h>

// QNetSNN: B=16384, HIDDEN=64, T=40.  R9: EXACT integer MFMA.
// R7/R8 failed with BIT-IDENTICAL absmax 0.2666 despite different lo-plane
// bits -> FTZ was never the leak; the f32 MFMA accumulation-order deviation
// (~1-2e-6, incl. i_dec-seeded accumulators knocking adds off-grid) exceeds
// the reference's own ~8e-7 rounding, and the spiking recurrence avalanches
// the extra threshold flips (R4 evidence: deviation == ref's own error ->
// absmax 0.0117 passes; 2-3x flips -> 0.2666).
// Fix: spikes are {0,1}, so make sums EXACT. Weights as 4 signed-7-bit
// digits, w ~= 2^-25*(d3*2^21 + d2*2^14 + d1*2^7 + d0), residual <= 2^-27.
// Each digit plane via mfma_i32_16x16x64_i8: i32 accumulation = ZERO
// rounding (|sums| <= 2^13). Planes combined pairwise in i32 (exact) then
// two f32 fmas into i_dec. Deviation vs truth ~1e-7 << ref's 1e-6 ->
// flip set ~= R4's (passed at 0.0117).
// Also: quantization fused into the main kernel (no prep, no d_ws).
//
// Structure: wave = 16 batch rows; D[n][m] = sum_k W[n][k] z[m][k];
// WS/WC digit planes register-resident (launch_bounds(256,1), 512 VGPR);
// WA planes in LDS; spike D->B transposes via wave-private byte buffers.
//
// LDS (51200 B): [0,32768) WA planes [4][64][128] i8 (init: scratch for
//   WS then WC quantization) | [32768,40960) bufS 4w x [16][128] i8 |
//   [40960,51200) bufAC 4w x [16][160] i8.
// bufS  cols: 0..47 enc_state | 48..111 z_c | 112..127 zero
// bufAC cols: 0..7 enc_act | 8..15 zero | 16..79 z_s | 80..143 z_a | pad
// WS k: 0..47 Wsin | 48..111 Wsrec | 112..127 zero
// WA k: 0..7 Wain | 8..15 zero | 16..79 Warec | 80..127 zero
// WC k: 0..63 Wcin1 (z_s) | 64..127 Wcin2+Wcrec fold (z_a); B base col 16.

typedef int   i32x4 __attribute__((ext_vector_type(4)));
typedef float f32x4 __attribute__((ext_vector_type(4)));

__launch_bounds__(256, 1)
__global__ void snn_main(const float* __restrict__ state, const float* __restrict__ action,
                         const float* __restrict__ Wsin, const float* __restrict__ Wsrec,
                         const float* __restrict__ Wain, const float* __restrict__ Warec,
                         const float* __restrict__ Wcin, const float* __restrict__ Wcrec,
                         const float* __restrict__ Wro, float* __restrict__ out) {
    __shared__ __align__(16) char smem[51200];

    const int tid  = threadIdx.x;
    const int lane = tid & 63, wv = tid >> 6;
    const int l15  = lane & 15, g = lane >> 4;

    // ---- quantize one weight into 4 signed-7-bit digits (all steps exact) ----
    auto quant = [](float w, int* d) {
        float x = w * 0x1p25f;                                   // exact (pow2)
        int d3 = __float2int_rn(x * 0x1p-21f); x -= (float)d3 * 0x1p21f;
        int d2 = __float2int_rn(x * 0x1p-14f); x -= (float)d2 * 0x1p14f;
        int d1 = __float2int_rn(x * 0x1p-7f);  x -= (float)d1 * 0x1p7f;
        int d0 = __float2int_rn(x);                              // residual <= 0.5 int = 2^-27
        d[0] = d0; d[1] = d1; d[2] = d2; d[3] = d3;
    };
    auto quantMat = [&](auto src) {   // quantize 64x128 matrix into smem[0,32768) as 4 planes
        for (int i4 = tid; i4 < 2048; i4 += 256) {
            int base = i4 * 4; int n = base >> 7, k0 = base & 127;
            uint32_t pk[4] = {0u, 0u, 0u, 0u};
            #pragma unroll
            for (int e = 0; e < 4; ++e) {
                int d[4]; quant(src(n, k0 + e), d);
                #pragma unroll
                for (int p = 0; p < 4; ++p) pk[p] |= (uint32_t)(uint8_t)(char)d[p] << (8 * e);
            }
            #pragma unroll
            for (int p = 0; p < 4; ++p) *(uint32_t*)(smem + p * 8192 + base) = pk[p];
        }
    };

    i32x4 AS[4][4][2], AC[4][4][2];   // [plane][nt][kt] register-resident A-frags

    quantMat([&](int n, int k) -> float {
        if (k < 48)  return Wsin[n * 48 + k];
        if (k < 112) return Wsrec[n * 64 + (k - 48)];
        return 0.f;
    });
    __syncthreads();
    #pragma unroll
    for (int p = 0; p < 4; ++p)
    #pragma unroll
    for (int nt = 0; nt < 4; ++nt)
    #pragma unroll
    for (int kt = 0; kt < 2; ++kt)
        AS[p][nt][kt] = *(const i32x4*)(smem + p * 8192 + (16 * nt + l15) * 128 + 64 * kt + 16 * g);
    __syncthreads();

    quantMat([&](int n, int k) -> float {
        float w = Wcin[n * 128 + k];
        if (k >= 64) w += Wcrec[n * 64 + (k - 64)];   // fold (exact-match to R6, absmax 0.0)
        return w;
    });
    __syncthreads();
    #pragma unroll
    for (int p = 0; p < 4; ++p)
    #pragma unroll
    for (int nt = 0; nt < 4; ++nt)
    #pragma unroll
    for (int kt = 0; kt < 2; ++kt)
        AC[p][nt][kt] = *(const i32x4*)(smem + p * 8192 + (16 * nt + l15) * 128 + 64 * kt + 16 * g);
    __syncthreads();

    quantMat([&](int n, int k) -> float {   // WA stays resident in LDS
        if (k < 8)              return Wain[n * 8 + k];
        if (k >= 16 && k < 80)  return Warec[n * 64 + (k - 16)];
        return 0.f;
    });
    for (int i = tid; i < 4608; i += 256) ((uint32_t*)(smem + 32768))[i] = 0u;  // staging zero
    __syncthreads();

    char* bS  = smem + 32768 + wv * 2048;   // [16][128] i8
    char* bAC = smem + 40960 + wv * 2560;   // [16][160] i8

    const int rowBase = blockIdx.x * 64 + wv * 16;
    const int row = rowBase + l15;

    // encoder currents, B-layout: feature f = t2*32 + 8g + e
    float cur[16];
    #pragma unroll
    for (int t2 = 0; t2 < 2; ++t2)
    #pragma unroll
    for (int e = 0; e < 8; ++e) {
        int f = t2 * 32 + 8 * g + e;
        float c = 0.f;
        if (f < 24)      c = fmaxf( 50.f * state[row * 24 + f], 0.f);
        else if (f < 48) c = fmaxf(-50.f * state[row * 24 + f - 24], 0.f);
        else if (f < 52) c = fmaxf( 50.f * action[row * 4 + f - 48], 0.f);
        else if (f < 56) c = fmaxf(-50.f * action[row * 4 + f - 52], 0.f);
        cur[t2 * 8 + e] = c;
    }

    float wrof[4][4];   // D-layout: n = 16j + 4g + r
    #pragma unroll
    for (int j = 0; j < 4; ++j)
    #pragma unroll
    for (int r = 0; r < 4; ++r) wrof[j][r] = Wro[16 * j + 4 * g + r];

    float venc[16];
    #pragma unroll
    for (int i = 0; i < 16; ++i) venc[i] = 0.f;
    f32x4 v4[4], ic4[4];
    #pragma unroll
    for (int j = 0; j < 4; ++j) { v4[j] = (f32x4){0.f,0.f,0.f,0.f}; ic4[j] = (f32x4){0.f,0.f,0.f,0.f}; }
    float vli = 0.f, ili = 0.f, vmax = 0.f;

    for (int t = 0; t < 40; ++t) {
        // ---- layer-s threshold (entering v, icur) ----
        f32x4 vs[4]; bool zs[4][4];
        #pragma unroll
        for (int j = 0; j < 4; ++j) {
            f32x4 vd = v4[j] + 0.1f * (ic4[j] - v4[j]);
            #pragma unroll
            for (int r = 0; r < 4; ++r) { zs[j][r] = (vd[r] - 1.0f) > 0.f; if (zs[j][r]) vd[r] = 0.f; }
            vs[j] = vd;
        }
        #pragma unroll
        for (int j = 0; j < 4; ++j) {   // stage z_s -> bufAC cols 16..79
            uint32_t zw = (zs[j][0]?1u:0u)|(zs[j][1]?0x100u:0u)|(zs[j][2]?0x10000u:0u)|(zs[j][3]?0x1000000u:0u);
            *(uint32_t*)(bAC + l15 * 160 + 16 + 16 * j + 4 * g) = zw;
        }

        // ---- encoder update + stage spike bytes ----
        uint32_t ew[4];
        #pragma unroll
        for (int h = 0; h < 4; ++h) {
            uint32_t wrd = 0;
            #pragma unroll
            for (int e = 0; e < 4; ++e) {
                int i = h * 4 + e;
                float vn = venc[i] + 0.1f * (cur[i] - venc[i]);
                bool sp = (vn - 1.0f) > 0.f;
                venc[i] = sp ? 0.f : vn;
                wrd |= sp ? (1u << (8 * e)) : 0u;
            }
            ew[h] = wrd;
        }
        *(uint2*)(bS + l15 * 128 + 8 * g) = make_uint2(ew[0], ew[1]);            // f 0..31
        if (g < 2)       *(uint2*)(bS + l15 * 128 + 32 + 8 * g) = make_uint2(ew[2], ew[3]);  // f 32..47
        else if (g == 2) *(uint2*)(bAC + l15 * 160)             = make_uint2(ew[2], ew[3]);  // f 48..55

        // ---- layer-s matmul: zero-seeded exact i32 planes ----
        i32x4 acc[4][4];
        #pragma unroll
        for (int p = 0; p < 4; ++p)
        #pragma unroll
        for (int nt = 0; nt < 4; ++nt) acc[p][nt] = (i32x4){0,0,0,0};
        asm volatile("" ::: "memory");
        #pragma unroll
        for (int kt = 0; kt < 2; ++kt) {
            i32x4 b = *(const i32x4*)(bS + l15 * 128 + 64 * kt + 16 * g);
            #pragma unroll
            for (int p = 0; p < 4; ++p)
            #pragma unroll
            for (int nt = 0; nt < 4; ++nt)
                acc[p][nt] = __builtin_amdgcn_mfma_i32_16x16x64_i8(AS[p][nt][kt], b, acc[p][nt], 0, 0, 0);
        }
        f32x4 icS[4];
        #pragma unroll
        for (int nt = 0; nt < 4; ++nt) {
            i32x4 hi = acc[3][nt] * 128 + acc[2][nt];   // exact i32
            i32x4 lo = acc[1][nt] * 128 + acc[0][nt];
            f32x4 idec = ic4[nt] - 0.2f * ic4[nt];
            #pragma unroll
            for (int r = 0; r < 4; ++r)
                icS[nt][r] = fmaf((float)lo[r], 0x1p-25f, fmaf((float)hi[r], 0x1p-11f, idec[r]));
        }

        // ---- layer-a threshold ----
        f32x4 va[4]; bool za[4][4];
        #pragma unroll
        for (int j = 0; j < 4; ++j) {
            f32x4 vd = vs[j] + 0.1f * (icS[j] - vs[j]);
            #pragma unroll
            for (int r = 0; r < 4; ++r) { za[j][r] = (vd[r] - 1.0f) > 0.f; if (za[j][r]) vd[r] = 0.f; }
            va[j] = vd;
        }
        #pragma unroll
        for (int j = 0; j < 4; ++j) {   // stage z_a -> bufAC cols 80..143
            uint32_t zw = (za[j][0]?1u:0u)|(za[j][1]?0x100u:0u)|(za[j][2]?0x10000u:0u)|(za[j][3]?0x1000000u:0u);
            *(uint32_t*)(bAC + l15 * 160 + 80 + 16 * j + 4 * g) = zw;
        }

        // ---- layer-a matmul (WA planes from LDS) ----
        #pragma unroll
        for (int p = 0; p < 4; ++p)
        #pragma unroll
        for (int nt = 0; nt < 4; ++nt) acc[p][nt] = (i32x4){0,0,0,0};
        asm volatile("" ::: "memory");
        #pragma unroll
        for (int kt = 0; kt < 2; ++kt) {
            i32x4 b = *(const i32x4*)(bAC + l15 * 160 + 64 * kt + 16 * g);
            #pragma unroll
            for (int p = 0; p < 4; ++p)
            #pragma unroll
            for (int nt = 0; nt < 4; ++nt) {
                i32x4 a = *(const i32x4*)(smem + p * 8192 + (16 * nt + l15) * 128 + 64 * kt + 16 * g);
                acc[p][nt] = __builtin_amdgcn_mfma_i32_16x16x64_i8(a, b, acc[p][nt], 0, 0, 0);
            }
        }
        f32x4 icA[4];
        #pragma unroll
        for (int nt = 0; nt < 4; ++nt) {
            i32x4 hi = acc[3][nt] * 128 + acc[2][nt];
            i32x4 lo = acc[1][nt] * 128 + acc[0][nt];
            f32x4 idec = icS[nt] - 0.2f * icS[nt];
            #pragma unroll
            for (int r = 0; r < 4; ++r)
                icA[nt][r] = fmaf((float)lo[r], 0x1p-25f, fmaf((float)hi[r], 0x1p-11f, idec[r]));
        }

        // ---- layer-c threshold (yields z_c and persisted v) ----
        bool zc[4][4];
        #pragma unroll
        for (int j = 0; j < 4; ++j) {
            f32x4 vd = va[j] + 0.1f * (icA[j] - va[j]);
            #pragma unroll
            for (int r = 0; r < 4; ++r) { zc[j][r] = (vd[r] - 1.0f) > 0.f; if (zc[j][r]) vd[r] = 0.f; }
            v4[j] = vd;
        }
        #pragma unroll
        for (int j = 0; j < 4; ++j) {   // stage z_c -> bufS cols 48..111 (next step)
            uint32_t zw = (zc[j][0]?1u:0u)|(zc[j][1]?0x100u:0u)|(zc[j][2]?0x10000u:0u)|(zc[j][3]?0x1000000u:0u);
            *(uint32_t*)(bS + l15 * 128 + 48 + 16 * j + 4 * g) = zw;
        }

        // ---- layer-c matmul ([z_s|z_a] @ WC^T, B base col 16) ----
        #pragma unroll
        for (int p = 0; p < 4; ++p)
        #pragma unroll
        for (int nt = 0; nt < 4; ++nt) acc[p][nt] = (i32x4){0,0,0,0};
        asm volatile("" ::: "memory");
        #pragma unroll
        for (int kt = 0; kt < 2; ++kt) {
            i32x4 b = *(const i32x4*)(bAC + l15 * 160 + 16 + 64 * kt + 16 * g);
            #pragma unroll
            for (int p = 0; p < 4; ++p)
            #pragma unroll
            for (int nt = 0; nt < 4; ++nt)
                acc[p][nt] = __builtin_amdgcn_mfma_i32_16x16x64_i8(AC[p][nt][kt], b, acc[p][nt], 0, 0, 0);
        }
        #pragma unroll
        for (int nt = 0; nt < 4; ++nt) {
            i32x4 hi = acc[3][nt] * 128 + acc[2][nt];
            i32x4 lo = acc[1][nt] * 128 + acc[0][nt];
            f32x4 idec = icA[nt] - 0.2f * icA[nt];
            #pragma unroll
            for (int r = 0; r < 4; ++r)
                ic4[nt][r] = fmaf((float)lo[r], 0x1p-25f, fmaf((float)hi[r], 0x1p-11f, idec[r]));
        }

        // ---- LI readout (feed-forward, f32) ----
        float p = 0.f;
        #pragma unroll
        for (int j = 0; j < 4; ++j)
        #pragma unroll
        for (int r = 0; r < 4; ++r) p += zc[j][r] ? wrof[j][r] : 0.f;
        p += __shfl_xor(p, 16);
        p += __shfl_xor(p, 32);
        float vnew = vli + 0.1f * (ili - vli);
        ili = (ili - 0.2f * ili) + p;
        vli = vnew;
        vmax = fmaxf(vmax, vli);
    }

    if (g == 0) out[rowBase + l15] = vmax;
}

extern "C" void kernel_launch(void* const* d_in, const int* in_sizes, int n_in,
                              void* d_out, int out_size, void* d_ws, size_t ws_size,
                              hipStream_t stream) {
    const float* state  = (const float*)d_in[0];
    const float* action = (const float*)d_in[1];
    const float* Wsin   = (const float*)d_in[2];
    const float* Wsrec  = (const float*)d_in[3];
    const float* Wain   = (const float*)d_in[4];
    const float* Warec  = (const float*)d_in[5];
    const float* Wcin   = (const float*)d_in[6];
    const float* Wcrec  = (const float*)d_in[7];
    const float* Wro    = (const float*)d_in[8];
    float* out = (float*)d_out;

    const int B = in_sizes[0] / 24;  // 16384
    snn_main<<<B / 64, 256, 0, stream>>>(state, action, Wsin, Wsrec, Wain, Warec,
                                         Wcin, Wcrec, Wro, out);
}

// Round 6
// 228.065 us; speedup vs baseline: 1.0413x; 1.0413x over previous
//
#include <hip/hip_runtime.h>
#include <stdint.h>

// QNetSNN: B=16384, HIDDEN=64, T=40.  R10: R9 + full LDS XOR-swizzle.
// R9 passed (absmax 0.01171875, bit-identical to the f64 R4 run -> exact
// i32-sum theory confirmed) but ran 187us with SQ_LDS_BANK_CONFLICT=2.8e7:
// every hot LDS layout is row-major stride-128/160, so B-fragment reads
// (l15*128+16g) and layer-a's 32 A-plane ds_read_b128/step are 16-way
// bank-conflicted (~25% of cycles), fully exposed at 1 wave/SIMD (grid
// gives exactly 1024 waves = 1/SIMD; OccupancyPercent 11.5 is parallelism-
// limited, not resource-limited).
// Fix (T2): XOR-swizzle the 16B column slot with (row&7) on BOTH write and
// read sides for bufS, bufAC, and the WA planes; bufAC restrided 160->256
// so the swizzle involution stays within the row. Pure byte relocation ->
// arithmetic bit-identical; absmax must remain exactly 0.01171875.
//
// Layouts (logical, before swizzle):
//   WA planes [4][64][128] i8 @ smem[0,32768)  (init: also scratch for WS/WC)
//   bufS  4w x [16][128] i8 @ 32768: 0..47 enc_state | 48..111 z_c | 112+ zero
//   bufAC 4w x [16][256] i8 @ 40960: 0..7 enc_act | 8..15 zero(A) |
//         16..79 z_s | 80..143 z_a | rest unused
// Swizzle: physical byte = row*STRIDE + (((idx16&8) | ((idx16&7)^(row&7)))<<4)
//          + (byte&15), where idx16 = logical_byte>>4.
// WS k: 0..47 Wsin | 48..111 Wsrec | 112..127 zero
// WA k: 0..7 Wain | 8..15 zero | 16..79 Warec | 80..127 zero
// WC k: 0..63 Wcin1 (z_s) | 64..127 Wcin2+Wcrec fold (z_a); B base col 16.

typedef int   i32x4 __attribute__((ext_vector_type(4)));
typedef float f32x4 __attribute__((ext_vector_type(4)));

__launch_bounds__(256, 1)
__global__ void snn_main(const float* __restrict__ state, const float* __restrict__ action,
                         const float* __restrict__ Wsin, const float* __restrict__ Wsrec,
                         const float* __restrict__ Wain, const float* __restrict__ Warec,
                         const float* __restrict__ Wcin, const float* __restrict__ Wcrec,
                         const float* __restrict__ Wro, float* __restrict__ out) {
    __shared__ __align__(16) char smem[57344];

    const int tid  = threadIdx.x;
    const int lane = tid & 63, wv = tid >> 6;
    const int l15  = lane & 15, g = lane >> 4;
    const int s    = l15 & 7;   // row-swizzle key (row = l15 for all buffers)

    // ---- quantize one weight into 4 signed-7-bit digits (all steps exact) ----
    auto quant = [](float w, int* d) {
        float x = w * 0x1p25f;                                   // exact (pow2)
        int d3 = __float2int_rn(x * 0x1p-21f); x -= (float)d3 * 0x1p21f;
        int d2 = __float2int_rn(x * 0x1p-14f); x -= (float)d2 * 0x1p14f;
        int d1 = __float2int_rn(x * 0x1p-7f);  x -= (float)d1 * 0x1p7f;
        int d0 = __float2int_rn(x);                              // residual <= 2^-27
        d[0] = d0; d[1] = d1; d[2] = d2; d[3] = d3;
    };
    // quantize 64x128 matrix into smem[0,32768) as 4 planes, SWIZZLED rows
    auto quantMat = [&](auto src) {
        for (int i4 = tid; i4 < 2048; i4 += 256) {
            int base = i4 * 4; int n = base >> 7, k0 = base & 127;
            int sw = n * 128 + ((((k0 >> 4) ^ (n & 7)) << 4) | (k0 & 15));
            uint32_t pk[4] = {0u, 0u, 0u, 0u};
            #pragma unroll
            for (int e = 0; e < 4; ++e) {
                int d[4]; quant(src(n, k0 + e), d);
                #pragma unroll
                for (int p = 0; p < 4; ++p) pk[p] |= (uint32_t)(uint8_t)(char)d[p] << (8 * e);
            }
            #pragma unroll
            for (int p = 0; p < 4; ++p) *(uint32_t*)(smem + p * 8192 + sw) = pk[p];
        }
    };

    // swizzled 16B-column offsets (bytes), row key s, col idx16 = 4kt+g etc.
    const int cS0 = ((g ^ s) << 4);             // idx16 = g        (kt=0)
    const int cS1 = (((4 + g) ^ s) << 4);       // idx16 = 4+g      (kt=1)
    const int i1c = 5 + g;
    const int cC0 = (((1 + g) ^ s) << 4);                        // layer-c kt=0
    const int cC1 = (((i1c & 8) | ((i1c & 7) ^ s)) << 4);        // layer-c kt=1

    i32x4 AS[4][4][2], AC[4][4][2];   // [plane][nt][kt] register-resident A-frags

    quantMat([&](int n, int k) -> float {
        if (k < 48)  return Wsin[n * 48 + k];
        if (k < 112) return Wsrec[n * 64 + (k - 48)];
        return 0.f;
    });
    __syncthreads();
    #pragma unroll
    for (int p = 0; p < 4; ++p)
    #pragma unroll
    for (int nt = 0; nt < 4; ++nt)
    #pragma unroll
    for (int kt = 0; kt < 2; ++kt)
        AS[p][nt][kt] = *(const i32x4*)(smem + p * 8192 + (16 * nt + l15) * 128 + (kt ? cS1 : cS0));
    __syncthreads();

    quantMat([&](int n, int k) -> float {
        float w = Wcin[n * 128 + k];
        if (k >= 64) w += Wcrec[n * 64 + (k - 64)];   // fold (matches R6, absmax 0.0)
        return w;
    });
    __syncthreads();
    #pragma unroll
    for (int p = 0; p < 4; ++p)
    #pragma unroll
    for (int nt = 0; nt < 4; ++nt)
    #pragma unroll
    for (int kt = 0; kt < 2; ++kt)
        AC[p][nt][kt] = *(const i32x4*)(smem + p * 8192 + (16 * nt + l15) * 128 + (kt ? cS1 : cS0));
    __syncthreads();

    quantMat([&](int n, int k) -> float {   // WA stays resident in LDS (swizzled)
        if (k < 8)              return Wain[n * 8 + k];
        if (k >= 16 && k < 80)  return Warec[n * 64 + (k - 16)];
        return 0.f;
    });
    for (int i = tid; i < 6144; i += 256) ((uint32_t*)(smem + 32768))[i] = 0u;  // zero bufS+bufAC
    __syncthreads();

    char* bS  = smem + 32768 + wv * 2048;   // [16][128] i8, swizzled
    char* bAC = smem + 40960 + wv * 4096;   // [16][256] i8, swizzled

    const int rowBase = blockIdx.x * 64 + wv * 16;
    const int row = rowBase + l15;

    // encoder currents, B-layout: feature f = t2*32 + 8g + e
    float cur[16];
    #pragma unroll
    for (int t2 = 0; t2 < 2; ++t2)
    #pragma unroll
    for (int e = 0; e < 8; ++e) {
        int f = t2 * 32 + 8 * g + e;
        float c = 0.f;
        if (f < 24)      c = fmaxf( 50.f * state[row * 24 + f], 0.f);
        else if (f < 48) c = fmaxf(-50.f * state[row * 24 + f - 24], 0.f);
        else if (f < 52) c = fmaxf( 50.f * action[row * 4 + f - 48], 0.f);
        else if (f < 56) c = fmaxf(-50.f * action[row * 4 + f - 52], 0.f);
        cur[t2 * 8 + e] = c;
    }

    float wrof[4][4];   // D-layout: n = 16j + 4g + r
    #pragma unroll
    for (int j = 0; j < 4; ++j)
    #pragma unroll
    for (int r = 0; r < 4; ++r) wrof[j][r] = Wro[16 * j + 4 * g + r];

    float venc[16];
    #pragma unroll
    for (int i = 0; i < 16; ++i) venc[i] = 0.f;
    f32x4 v4[4], ic4[4];
    #pragma unroll
    for (int j = 0; j < 4; ++j) { v4[j] = (f32x4){0.f,0.f,0.f,0.f}; ic4[j] = (f32x4){0.f,0.f,0.f,0.f}; }
    float vli = 0.f, ili = 0.f, vmax = 0.f;

    for (int t = 0; t < 40; ++t) {
        // ---- layer-s threshold (entering v, icur) ----
        f32x4 vs[4]; bool zs[4][4];
        #pragma unroll
        for (int j = 0; j < 4; ++j) {
            f32x4 vd = v4[j] + 0.1f * (ic4[j] - v4[j]);
            #pragma unroll
            for (int r = 0; r < 4; ++r) { zs[j][r] = (vd[r] - 1.0f) > 0.f; if (zs[j][r]) vd[r] = 0.f; }
            vs[j] = vd;
        }
        #pragma unroll
        for (int j = 0; j < 4; ++j) {   // stage z_s -> bufAC logical cols 16+16j (idx16 = 1+j)
            uint32_t zw = (zs[j][0]?1u:0u)|(zs[j][1]?0x100u:0u)|(zs[j][2]?0x10000u:0u)|(zs[j][3]?0x1000000u:0u);
            *(uint32_t*)(bAC + l15 * 256 + ((((1 + j) ^ s)) << 4) + 4 * g) = zw;
        }

        // ---- encoder update + stage spike bytes ----
        uint32_t ew[4];
        #pragma unroll
        for (int h = 0; h < 4; ++h) {
            uint32_t wrd = 0;
            #pragma unroll
            for (int e = 0; e < 4; ++e) {
                int i = h * 4 + e;
                float vn = venc[i] + 0.1f * (cur[i] - venc[i]);
                bool sp = (vn - 1.0f) > 0.f;
                venc[i] = sp ? 0.f : vn;
                wrd |= sp ? (1u << (8 * e)) : 0u;
            }
            ew[h] = wrd;
        }
        // enc f 8g..8g+7 -> bufS logical col 8g: idx16 = g>>1, intra = 8*(g&1)
        *(uint2*)(bS + l15 * 128 + ((((g >> 1) ^ s) << 4) | (8 * (g & 1)))) = make_uint2(ew[0], ew[1]);
        if (g < 2)        // f 32+8g: idx16 = 2, intra = 8g
            *(uint2*)(bS + l15 * 128 + (((2 ^ s) << 4) | (8 * g))) = make_uint2(ew[2], ew[3]);
        else if (g == 2)  // f 48..55 -> bufAC logical col 0: idx16 = 0
            *(uint2*)(bAC + l15 * 256 + (s << 4)) = make_uint2(ew[2], ew[3]);

        // ---- layer-s matmul: zero-seeded exact i32 planes ----
        i32x4 acc[4][4];
        #pragma unroll
        for (int p = 0; p < 4; ++p)
        #pragma unroll
        for (int nt = 0; nt < 4; ++nt) acc[p][nt] = (i32x4){0,0,0,0};
        asm volatile("" ::: "memory");
        #pragma unroll
        for (int kt = 0; kt < 2; ++kt) {
            i32x4 b = *(const i32x4*)(bS + l15 * 128 + (kt ? cS1 : cS0));
            #pragma unroll
            for (int p = 0; p < 4; ++p)
            #pragma unroll
            for (int nt = 0; nt < 4; ++nt)
                acc[p][nt] = __builtin_amdgcn_mfma_i32_16x16x64_i8(AS[p][nt][kt], b, acc[p][nt], 0, 0, 0);
        }
        f32x4 icS[4];
        #pragma unroll
        for (int nt = 0; nt < 4; ++nt) {
            i32x4 hi = acc[3][nt] * 128 + acc[2][nt];   // exact i32
            i32x4 lo = acc[1][nt] * 128 + acc[0][nt];
            f32x4 idec = ic4[nt] - 0.2f * ic4[nt];
            #pragma unroll
            for (int r = 0; r < 4; ++r)
                icS[nt][r] = fmaf((float)lo[r], 0x1p-25f, fmaf((float)hi[r], 0x1p-11f, idec[r]));
        }

        // ---- layer-a threshold ----
        f32x4 va[4]; bool za[4][4];
        #pragma unroll
        for (int j = 0; j < 4; ++j) {
            f32x4 vd = vs[j] + 0.1f * (icS[j] - vs[j]);
            #pragma unroll
            for (int r = 0; r < 4; ++r) { za[j][r] = (vd[r] - 1.0f) > 0.f; if (za[j][r]) vd[r] = 0.f; }
            va[j] = vd;
        }
        #pragma unroll
        for (int j = 0; j < 4; ++j) {   // stage z_a -> bufAC logical cols 80+16j (idx16 = 5+j)
            uint32_t zw = (za[j][0]?1u:0u)|(za[j][1]?0x100u:0u)|(za[j][2]?0x10000u:0u)|(za[j][3]?0x1000000u:0u);
            int ix = 5 + j;
            *(uint32_t*)(bAC + l15 * 256 + (((ix & 8) | ((ix & 7) ^ s)) << 4) + 4 * g) = zw;
        }

        // ---- layer-a matmul (WA planes from LDS, swizzled reads) ----
        #pragma unroll
        for (int p = 0; p < 4; ++p)
        #pragma unroll
        for (int nt = 0; nt < 4; ++nt) acc[p][nt] = (i32x4){0,0,0,0};
        asm volatile("" ::: "memory");
        #pragma unroll
        for (int kt = 0; kt < 2; ++kt) {
            i32x4 b = *(const i32x4*)(bAC + l15 * 256 + (kt ? cS1 : cS0));
            #pragma unroll
            for (int p = 0; p < 4; ++p)
            #pragma unroll
            for (int nt = 0; nt < 4; ++nt) {
                i32x4 a = *(const i32x4*)(smem + p * 8192 + (16 * nt + l15) * 128 + (kt ? cS1 : cS0));
                acc[p][nt] = __builtin_amdgcn_mfma_i32_16x16x64_i8(a, b, acc[p][nt], 0, 0, 0);
            }
        }
        f32x4 icA[4];
        #pragma unroll
        for (int nt = 0; nt < 4; ++nt) {
            i32x4 hi = acc[3][nt] * 128 + acc[2][nt];
            i32x4 lo = acc[1][nt] * 128 + acc[0][nt];
            f32x4 idec = icS[nt] - 0.2f * icS[nt];
            #pragma unroll
            for (int r = 0; r < 4; ++r)
                icA[nt][r] = fmaf((float)lo[r], 0x1p-25f, fmaf((float)hi[r], 0x1p-11f, idec[r]));
        }

        // ---- layer-c threshold (yields z_c and persisted v) ----
        bool zc[4][4];
        #pragma unroll
        for (int j = 0; j < 4; ++j) {
            f32x4 vd = va[j] + 0.1f * (icA[j] - va[j]);
            #pragma unroll
            for (int r = 0; r < 4; ++r) { zc[j][r] = (vd[r] - 1.0f) > 0.f; if (zc[j][r]) vd[r] = 0.f; }
            v4[j] = vd;
        }
        #pragma unroll
        for (int j = 0; j < 4; ++j) {   // stage z_c -> bufS logical cols 48+16j (idx16 = 3+j)
            uint32_t zw = (zc[j][0]?1u:0u)|(zc[j][1]?0x100u:0u)|(zc[j][2]?0x10000u:0u)|(zc[j][3]?0x1000000u:0u);
            *(uint32_t*)(bS + l15 * 128 + (((3 + j) ^ s) << 4) + 4 * g) = zw;
        }

        // ---- layer-c matmul ([z_s|z_a] @ WC^T, B logical base col 16) ----
        #pragma unroll
        for (int p = 0; p < 4; ++p)
        #pragma unroll
        for (int nt = 0; nt < 4; ++nt) acc[p][nt] = (i32x4){0,0,0,0};
        asm volatile("" ::: "memory");
        #pragma unroll
        for (int kt = 0; kt < 2; ++kt) {
            i32x4 b = *(const i32x4*)(bAC + l15 * 256 + (kt ? cC1 : cC0));
            #pragma unroll
            for (int p = 0; p < 4; ++p)
            #pragma unroll
            for (int nt = 0; nt < 4; ++nt)
                acc[p][nt] = __builtin_amdgcn_mfma_i32_16x16x64_i8(AC[p][nt][kt], b, acc[p][nt], 0, 0, 0);
        }
        #pragma unroll
        for (int nt = 0; nt < 4; ++nt) {
            i32x4 hi = acc[3][nt] * 128 + acc[2][nt];
            i32x4 lo = acc[1][nt] * 128 + acc[0][nt];
            f32x4 idec = icA[nt] - 0.2f * icA[nt];
            #pragma unroll
            for (int r = 0; r < 4; ++r)
                ic4[nt][r] = fmaf((float)lo[r], 0x1p-25f, fmaf((float)hi[r], 0x1p-11f, idec[r]));
        }

        // ---- LI readout (feed-forward, f32) ----
        float p = 0.f;
        #pragma unroll
        for (int j = 0; j < 4; ++j)
        #pragma unroll
        for (int r = 0; r < 4; ++r) p += zc[j][r] ? wrof[j][r] : 0.f;
        p += __shfl_xor(p, 16);
        p += __shfl_xor(p, 32);
        float vnew = vli + 0.1f * (ili - vli);
        ili = (ili - 0.2f * ili) + p;
        vli = vnew;
        vmax = fmaxf(vmax, vli);
    }

    if (g == 0) out[rowBase + l15] = vmax;
}

extern "C" void kernel_launch(void* const* d_in, const int* in_sizes, int n_in,
                              void* d_out, int out_size, void* d_ws, size_t ws_size,
                              hipStream_t stream) {
    const float* state  = (const float*)d_in[0];
    const float* action = (const float*)d_in[1];
    const float* Wsin   = (const float*)d_in[2];
    const float* Wsrec  = (const float*)d_in[3];
    const float* Wain   = (const float*)d_in[4];
    const float* Warec  = (const float*)d_in[5];
    const float* Wcin   = (const float*)d_in[6];
    const float* Wcrec  = (const float*)d_in[7];
    const float* Wro    = (const float*)d_in[8];
    float* out = (float*)d_out;

    const int B = in_sizes[0] / 24;  // 16384
    snn_main<<<B / 64, 256, 0, stream>>>(state, action, Wsin, Wsrec, Wain, Warec,
                                         Wcin, Wcrec, Wro, out);
}

// Round 7
// 191.715 us; speedup vs baseline: 1.2387x; 1.1896x over previous
//
#include <hip/hip_runtime.h>
#include <stdint.h>

// QNetSNN: B=16384, HIDDEN=64, T=40.  R11: N-split for 2 waves/SIMD.
// R10: swizzle killed conflicts (2.8e7->1.8e6) but dur only 187->177us ->
// conflicts weren't critical-path. Real limiter: occupancy = exactly
// 1 wave/SIMD (1024 row-group waves on 1024 SIMDs), so each wave's serial
// threshold->stage->ds_read->MFMA->combine chain is fully latency-exposed
// (MfmaUtil 15%, VALUBusy 47%, ~38% stall; MFMA floor is only ~33us).
// Fix: split the 64 neurons across 2 waves (2 n-tiles each) -> 2048 waves
// = 2/SIMD and 512 blocks = 2 independent blocks/CU; spike exchange via
// the existing byte-staging buffers + 3 barriers/step; bufAC parity
// double-buffered (t&1) to break the cross-iteration WAR; readout via
// 2 staged partials. Arithmetic unchanged (same exact i32 digit sums,
// same thresholds -> same spike trains); only readout add-order differs
// (f32 ~1e-7, no threshold downstream) -> absmax ~= 0.01171875.
//
// LDS (53504 B): [0,32768) WA planes [4][64][128] i8 swizzled (also quant
//   scratch for WS/WC) | [32768,36864) bufS 2rg x [16][128] |
//   [36864,53248) bufAC 2rg x 2par x [16][256] | [53248,53504) partials.
// Swizzle: physical = row*STRIDE + (((ix&8)|((ix&7)^(row&7)))<<4) + intra,
//   ix = logical_byte>>4 (identical to R10).
// WS k: 0..47 Wsin | 48..111 Wsrec | pad.  WA k: 0..7 Wain | 16..79 Warec.
// WC k: 0..63 Wcin1 (z_s) | 64..127 Wcin2+Wcrec fold (z_a).
// bufS cols: 0..47 enc | 48..111 z_c.  bufAC cols: 0..7 enc_a | 16..79 z_s
//   | 80..143 z_a.  Wave h owns neurons h*32..h*32+31 (staging ix += 2h).

typedef int   i32x4 __attribute__((ext_vector_type(4)));
typedef float f32x4 __attribute__((ext_vector_type(4)));

__launch_bounds__(256, 2)
__global__ void snn_main(const float* __restrict__ state, const float* __restrict__ action,
                         const float* __restrict__ Wsin, const float* __restrict__ Wsrec,
                         const float* __restrict__ Wain, const float* __restrict__ Warec,
                         const float* __restrict__ Wcin, const float* __restrict__ Wcrec,
                         const float* __restrict__ Wro, float* __restrict__ out) {
    __shared__ __align__(16) char smem[53504];

    const int tid  = threadIdx.x;
    const int lane = tid & 63, wv = tid >> 6;
    const int rg   = wv >> 1, h = wv & 1;       // row-group, neuron-half
    const int l15  = lane & 15, g = lane >> 4;
    const int s    = l15 & 7;                   // swizzle key (row = l15)

    // ---- quantize one weight into 4 signed-7-bit digits (all steps exact) ----
    auto quant = [](float w, int* d) {
        float x = w * 0x1p25f;                                   // exact (pow2)
        int d3 = __float2int_rn(x * 0x1p-21f); x -= (float)d3 * 0x1p21f;
        int d2 = __float2int_rn(x * 0x1p-14f); x -= (float)d2 * 0x1p14f;
        int d1 = __float2int_rn(x * 0x1p-7f);  x -= (float)d1 * 0x1p7f;
        int d0 = __float2int_rn(x);                              // residual <= 2^-27
        d[0] = d0; d[1] = d1; d[2] = d2; d[3] = d3;
    };
    auto quantMat = [&](auto src) {   // 64x128 -> smem[0,32768) 4 planes, swizzled rows
        for (int i4 = tid; i4 < 2048; i4 += 256) {
            int base = i4 * 4; int n = base >> 7, k0 = base & 127;
            int sw = n * 128 + ((((k0 >> 4) ^ (n & 7)) << 4) | (k0 & 15));
            uint32_t pk[4] = {0u, 0u, 0u, 0u};
            #pragma unroll
            for (int e = 0; e < 4; ++e) {
                int d[4]; quant(src(n, k0 + e), d);
                #pragma unroll
                for (int p = 0; p < 4; ++p) pk[p] |= (uint32_t)(uint8_t)(char)d[p] << (8 * e);
            }
            #pragma unroll
            for (int p = 0; p < 4; ++p) *(uint32_t*)(smem + p * 8192 + sw) = pk[p];
        }
    };

    // swizzled 16B-slot offsets
    const int cS0 = ((g ^ s) << 4);             // B idx16 = g      (kt=0)
    const int cS1 = (((4 + g) ^ s) << 4);       // B idx16 = 4+g    (kt=1)
    const int i1c = 5 + g;
    const int cC0 = (((1 + g) ^ s) << 4);                        // layer-c kt=0
    const int cC1 = (((i1c & 8) | ((i1c & 7) ^ s)) << 4);        // layer-c kt=1

    i32x4 AS[4][2][2], AC[4][2][2];   // [plane][nt][kt], this wave's 32 neurons
    const int arow = (h * 32 + l15) * 128;

    quantMat([&](int n, int k) -> float {
        if (k < 48)  return Wsin[n * 48 + k];
        if (k < 112) return Wsrec[n * 64 + (k - 48)];
        return 0.f;
    });
    __syncthreads();
    #pragma unroll
    for (int p = 0; p < 4; ++p)
    #pragma unroll
    for (int nt = 0; nt < 2; ++nt)
    #pragma unroll
    for (int kt = 0; kt < 2; ++kt)
        AS[p][nt][kt] = *(const i32x4*)(smem + p * 8192 + arow + nt * 2048 + (kt ? cS1 : cS0));
    __syncthreads();

    quantMat([&](int n, int k) -> float {
        float w = Wcin[n * 128 + k];
        if (k >= 64) w += Wcrec[n * 64 + (k - 64)];   // fold (matches R6, absmax 0.0)
        return w;
    });
    __syncthreads();
    #pragma unroll
    for (int p = 0; p < 4; ++p)
    #pragma unroll
    for (int nt = 0; nt < 2; ++nt)
    #pragma unroll
    for (int kt = 0; kt < 2; ++kt)
        AC[p][nt][kt] = *(const i32x4*)(smem + p * 8192 + arow + nt * 2048 + (kt ? cS1 : cS0));
    __syncthreads();

    quantMat([&](int n, int k) -> float {   // WA resident in LDS
        if (k < 8)              return Wain[n * 8 + k];
        if (k >= 16 && k < 80)  return Warec[n * 64 + (k - 16)];
        return 0.f;
    });
    for (int i = tid; i < 5184; i += 256) ((uint32_t*)(smem + 32768))[i] = 0u;  // bufs+part
    __syncthreads();

    char*  bS   = smem + 32768 + rg * 2048;    // [16][128] swizzled
    char*  bAC0 = smem + 36864 + rg * 8192;    // 2 parity x [16][256] swizzled
    float* part = (float*)(smem + 53248 + rg * 128);

    const int rowBase = blockIdx.x * 32 + rg * 16;
    const int row = rowBase + l15;

    float cur[16], venc[16];
    #pragma unroll
    for (int i = 0; i < 16; ++i) { cur[i] = 0.f; venc[i] = 0.f; }
    if (h == 0) {   // encoder owned by half 0 (features are per-row, shared)
        #pragma unroll
        for (int t2 = 0; t2 < 2; ++t2)
        #pragma unroll
        for (int e = 0; e < 8; ++e) {
            int f = t2 * 32 + 8 * g + e;
            float c = 0.f;
            if (f < 24)      c = fmaxf( 50.f * state[row * 24 + f], 0.f);
            else if (f < 48) c = fmaxf(-50.f * state[row * 24 + f - 24], 0.f);
            else if (f < 52) c = fmaxf( 50.f * action[row * 4 + f - 48], 0.f);
            else if (f < 56) c = fmaxf(-50.f * action[row * 4 + f - 52], 0.f);
            cur[t2 * 8 + e] = c;
        }
    }

    float wrof[2][4];   // D-layout: n = h*32 + 16j + 4g + r
    #pragma unroll
    for (int j = 0; j < 2; ++j)
    #pragma unroll
    for (int r = 0; r < 4; ++r) wrof[j][r] = Wro[h * 32 + 16 * j + 4 * g + r];

    f32x4 v4[2], ic4[2];
    #pragma unroll
    for (int j = 0; j < 2; ++j) { v4[j] = (f32x4){0.f,0.f,0.f,0.f}; ic4[j] = (f32x4){0.f,0.f,0.f,0.f}; }
    float vli = 0.f, ili = 0.f, vmax = 0.f;

    for (int t = 0; t < 40; ++t) {
        char* bAC = bAC0 + ((t & 1) << 12);   // parity double-buffer

        // ---- layer-s threshold (entering v, icur) ----
        f32x4 vs[2]; bool zs[2][4];
        #pragma unroll
        for (int j = 0; j < 2; ++j) {
            f32x4 vd = v4[j] + 0.1f * (ic4[j] - v4[j]);
            #pragma unroll
            for (int r = 0; r < 4; ++r) { zs[j][r] = (vd[r] - 1.0f) > 0.f; if (zs[j][r]) vd[r] = 0.f; }
            vs[j] = vd;
        }
        #pragma unroll
        for (int j = 0; j < 2; ++j) {   // stage z_s: logical ix = 1 + 2h + j
            uint32_t zw = (zs[j][0]?1u:0u)|(zs[j][1]?0x100u:0u)|(zs[j][2]?0x10000u:0u)|(zs[j][3]?0x1000000u:0u);
            int ix = 1 + 2 * h + j;
            *(uint32_t*)(bAC + l15 * 256 + (((ix & 8) | ((ix & 7) ^ s)) << 4) + 4 * g) = zw;
        }

        // ---- encoder update + staging (half 0 only) ----
        if (h == 0) {
            uint32_t ew[4];
            #pragma unroll
            for (int h4 = 0; h4 < 4; ++h4) {
                uint32_t wrd = 0;
                #pragma unroll
                for (int e = 0; e < 4; ++e) {
                    int i = h4 * 4 + e;
                    float vn = venc[i] + 0.1f * (cur[i] - venc[i]);
                    bool sp = (vn - 1.0f) > 0.f;
                    venc[i] = sp ? 0.f : vn;
                    wrd |= sp ? (1u << (8 * e)) : 0u;
                }
                ew[h4] = wrd;
            }
            *(uint2*)(bS + l15 * 128 + ((((g >> 1) ^ s) << 4) | (8 * (g & 1)))) = make_uint2(ew[0], ew[1]);
            if (g < 2)
                *(uint2*)(bS + l15 * 128 + (((2 ^ s) << 4) | (8 * g))) = make_uint2(ew[2], ew[3]);
            else if (g == 2)
                *(uint2*)(bAC + l15 * 256 + (s << 4)) = make_uint2(ew[2], ew[3]);
        }

        __syncthreads();   // A: z_s + enc visible (z_c via prev C)

        // ---- layer-s matmul: exact i32 digit planes ----
        i32x4 acc[4][2];
        #pragma unroll
        for (int p = 0; p < 4; ++p)
        #pragma unroll
        for (int nt = 0; nt < 2; ++nt) acc[p][nt] = (i32x4){0,0,0,0};
        #pragma unroll
        for (int kt = 0; kt < 2; ++kt) {
            i32x4 b = *(const i32x4*)(bS + l15 * 128 + (kt ? cS1 : cS0));
            #pragma unroll
            for (int p = 0; p < 4; ++p)
            #pragma unroll
            for (int nt = 0; nt < 2; ++nt)
                acc[p][nt] = __builtin_amdgcn_mfma_i32_16x16x64_i8(AS[p][nt][kt], b, acc[p][nt], 0, 0, 0);
        }
        f32x4 icS[2];
        #pragma unroll
        for (int nt = 0; nt < 2; ++nt) {
            i32x4 hi = acc[3][nt] * 128 + acc[2][nt];
            i32x4 lo = acc[1][nt] * 128 + acc[0][nt];
            f32x4 idec = ic4[nt] - 0.2f * ic4[nt];
            #pragma unroll
            for (int r = 0; r < 4; ++r)
                icS[nt][r] = fmaf((float)lo[r], 0x1p-25f, fmaf((float)hi[r], 0x1p-11f, idec[r]));
        }

        // ---- layer-a threshold + stage z_a (ix = 5 + 2h + j) ----
        f32x4 va[2]; bool za[2][4];
        #pragma unroll
        for (int j = 0; j < 2; ++j) {
            f32x4 vd = vs[j] + 0.1f * (icS[j] - vs[j]);
            #pragma unroll
            for (int r = 0; r < 4; ++r) { za[j][r] = (vd[r] - 1.0f) > 0.f; if (za[j][r]) vd[r] = 0.f; }
            va[j] = vd;
        }
        #pragma unroll
        for (int j = 0; j < 2; ++j) {
            uint32_t zw = (za[j][0]?1u:0u)|(za[j][1]?0x100u:0u)|(za[j][2]?0x10000u:0u)|(za[j][3]?0x1000000u:0u);
            int ix = 5 + 2 * h + j;
            *(uint32_t*)(bAC + l15 * 256 + (((ix & 8) | ((ix & 7) ^ s)) << 4) + 4 * g) = zw;
        }

        __syncthreads();   // B: z_a visible

        // ---- layer-a matmul (WA planes from LDS) ----
        #pragma unroll
        for (int p = 0; p < 4; ++p)
        #pragma unroll
        for (int nt = 0; nt < 2; ++nt) acc[p][nt] = (i32x4){0,0,0,0};
        #pragma unroll
        for (int kt = 0; kt < 2; ++kt) {
            i32x4 b = *(const i32x4*)(bAC + l15 * 256 + (kt ? cS1 : cS0));
            #pragma unroll
            for (int p = 0; p < 4; ++p)
            #pragma unroll
            for (int nt = 0; nt < 2; ++nt) {
                i32x4 a = *(const i32x4*)(smem + p * 8192 + arow + nt * 2048 + (kt ? cS1 : cS0));
                acc[p][nt] = __builtin_amdgcn_mfma_i32_16x16x64_i8(a, b, acc[p][nt], 0, 0, 0);
            }
        }
        f32x4 icA[2];
        #pragma unroll
        for (int nt = 0; nt < 2; ++nt) {
            i32x4 hi = acc[3][nt] * 128 + acc[2][nt];
            i32x4 lo = acc[1][nt] * 128 + acc[0][nt];
            f32x4 idec = icS[nt] - 0.2f * icS[nt];
            #pragma unroll
            for (int r = 0; r < 4; ++r)
                icA[nt][r] = fmaf((float)lo[r], 0x1p-25f, fmaf((float)hi[r], 0x1p-11f, idec[r]));
        }

        // ---- layer-c threshold (yields z_c, persisted v) ----
        bool zc[2][4];
        #pragma unroll
        for (int j = 0; j < 2; ++j) {
            f32x4 vd = va[j] + 0.1f * (icA[j] - va[j]);
            #pragma unroll
            for (int r = 0; r < 4; ++r) { zc[j][r] = (vd[r] - 1.0f) > 0.f; if (zc[j][r]) vd[r] = 0.f; }
            v4[j] = vd;
        }
        #pragma unroll
        for (int j = 0; j < 2; ++j) {   // stage z_c: bufS ix = 3 + 2h + j
            uint32_t zw = (zc[j][0]?1u:0u)|(zc[j][1]?0x100u:0u)|(zc[j][2]?0x10000u:0u)|(zc[j][3]?0x1000000u:0u);
            int ix = 3 + 2 * h + j;
            *(uint32_t*)(bS + l15 * 128 + ((ix ^ s) << 4) + 4 * g) = zw;
        }
        // readout partial over this wave's 32 neurons
        float pr = 0.f;
        #pragma unroll
        for (int j = 0; j < 2; ++j)
        #pragma unroll
        for (int r = 0; r < 4; ++r) pr += zc[j][r] ? wrof[j][r] : 0.f;
        pr += __shfl_xor(pr, 16);
        pr += __shfl_xor(pr, 32);
        if (g == 0) part[h * 16 + l15] = pr;

        __syncthreads();   // C: z_c + partials visible

        // ---- layer-c matmul ([z_s|z_a] @ WC^T, logical base col 16) ----
        #pragma unroll
        for (int p = 0; p < 4; ++p)
        #pragma unroll
        for (int nt = 0; nt < 2; ++nt) acc[p][nt] = (i32x4){0,0,0,0};
        #pragma unroll
        for (int kt = 0; kt < 2; ++kt) {
            i32x4 b = *(const i32x4*)(bAC + l15 * 256 + (kt ? cC1 : cC0));
            #pragma unroll
            for (int p = 0; p < 4; ++p)
            #pragma unroll
            for (int nt = 0; nt < 2; ++nt)
                acc[p][nt] = __builtin_amdgcn_mfma_i32_16x16x64_i8(AC[p][nt][kt], b, acc[p][nt], 0, 0, 0);
        }
        #pragma unroll
        for (int nt = 0; nt < 2; ++nt) {
            i32x4 hi = acc[3][nt] * 128 + acc[2][nt];
            i32x4 lo = acc[1][nt] * 128 + acc[0][nt];
            f32x4 idec = icA[nt] - 0.2f * icA[nt];
            #pragma unroll
            for (int r = 0; r < 4; ++r)
                ic4[nt][r] = fmaf((float)lo[r], 0x1p-25f, fmaf((float)hi[r], 0x1p-11f, idec[r]));
        }

        // ---- LI readout (both halves' partials) ----
        float pt = part[l15] + part[16 + l15];
        float vnew = vli + 0.1f * (ili - vli);
        ili = (ili - 0.2f * ili) + pt;
        vli = vnew;
        vmax = fmaxf(vmax, vli);
    }

    if (h == 0 && g == 0) out[rowBase + l15] = vmax;
}

extern "C" void kernel_launch(void* const* d_in, const int* in_sizes, int n_in,
                              void* d_out, int out_size, void* d_ws, size_t ws_size,
                              hipStream_t stream) {
    const float* state  = (const float*)d_in[0];
    const float* action = (const float*)d_in[1];
    const float* Wsin   = (const float*)d_in[2];
    const float* Wsrec  = (const float*)d_in[3];
    const float* Wain   = (const float*)d_in[4];
    const float* Warec  = (const float*)d_in[5];
    const float* Wcin   = (const float*)d_in[6];
    const float* Wcrec  = (const float*)d_in[7];
    const float* Wro    = (const float*)d_in[8];
    float* out = (float*)d_out;

    const int B = in_sizes[0] / 24;  // 16384
    snn_main<<<B / 32, 256, 0, stream>>>(state, action, Wsin, Wsrec, Wain, Warec,
                                         Wcin, Wcrec, Wro, out);
}